// Round 1
// baseline (2302.225 us; speedup 1.0000x reference)
//
#include <hip/hip_runtime.h>

// LSTM: B=256 sequences, T=2048 steps, H=128, gates=4H=512.
// One batch row per workgroup (256 WGs = 256 CUs). 512 threads/WG:
// thread t owns gate row t of W_hh in 32 float4 VGPRs.
// Per step: phase A (all threads: matvec from h_lds + activation -> g_lds),
// barrier, phase B (wave 0: c/h update for 2 units/lane, fc dot + wave
// reduce, store out), barrier.

constexpr int NB = 256;   // batch
constexpr int NT = 2048;  // time steps
constexpr int NH = 128;   // hidden
constexpr int NG = 512;   // 4*NH gate rows

__device__ __forceinline__ float fast_sigmoid(float x) {
    x = fminf(fmaxf(x, -30.f), 30.f);
    return 1.f / (1.f + __expf(-x));
}

__device__ __forceinline__ float fast_tanh(float x) {
    x = fminf(fmaxf(x, -15.f), 15.f);
    float e = __expf(-2.f * x);          // exp(30) max = 1e13, no overflow
    return (1.f - e) / (1.f + e);
}

__global__ __launch_bounds__(512, 2) void lstm_fused_kernel(
    const float* __restrict__ x, const float* __restrict__ W_ih,
    const float* __restrict__ W_hh, const float* __restrict__ b_ih,
    const float* __restrict__ b_hh, const float* __restrict__ fc_w,
    const float* __restrict__ fc_b, float* __restrict__ out) {
    __shared__ __align__(16) float x_lds[NT];   // this batch's input row
    __shared__ __align__(16) float h_lds[NH];   // hidden state
    __shared__ __align__(16) float g_lds[NG];   // activated gates

    const int b = blockIdx.x;
    const int t = threadIdx.x;  // 0..511 = gate row index

    // ---- preload x row (coalesced float4: 512 threads x 1 float4 = 2048 f) ----
    {
        const float4* xs = (const float4*)(x + (size_t)b * NT);
        ((float4*)x_lds)[t] = xs[t];
    }
    if (t < NH) h_lds[t] = 0.f;

    // ---- per-thread weights: row t of W_hh (128 floats = 32 float4) ----
    float4 w[32];
    {
        const float4* wr = (const float4*)W_hh + t * 32;
#pragma unroll
        for (int k = 0; k < 32; ++k) w[k] = wr[k];
    }
    const float wih  = W_ih[t];
    const float bias = b_ih[t] + b_hh[t];
    const bool  is_g = ((t >> 7) == 2);  // rows 256..383 use tanh

    // ---- phase-B state (wave 0 only; lane l owns hidden units l and l+64) ----
    float c0 = 0.f, c1 = 0.f;
    float fcw0 = 0.f, fcw1 = 0.f, fcb = 0.f;
    if (t < 64) {
        fcw0 = fc_w[t];
        fcw1 = fc_w[t + 64];
        fcb  = fc_b[0];
    }

    float* outp = out + (size_t)b * NT;

    __syncthreads();

    for (int step = 0; step < NT; ++step) {
        // ================= phase A: all 512 threads =================
        // acc = x_t*W_ih[t] + b_ih[t] + b_hh[t] + dot(W_hh[t,:], h)
        float a0 = 0.f, a1 = 0.f, a2 = 0.f, a3 = 0.f;
        const float4* h4 = (const float4*)h_lds;
#pragma unroll
        for (int k = 0; k < 32; k += 4) {
            float4 v0 = h4[k + 0];
            float4 v1 = h4[k + 1];
            float4 v2 = h4[k + 2];
            float4 v3 = h4[k + 3];
            a0 = fmaf(w[k + 0].x, v0.x, a0);
            a0 = fmaf(w[k + 0].y, v0.y, a0);
            a0 = fmaf(w[k + 0].z, v0.z, a0);
            a0 = fmaf(w[k + 0].w, v0.w, a0);
            a1 = fmaf(w[k + 1].x, v1.x, a1);
            a1 = fmaf(w[k + 1].y, v1.y, a1);
            a1 = fmaf(w[k + 1].z, v1.z, a1);
            a1 = fmaf(w[k + 1].w, v1.w, a1);
            a2 = fmaf(w[k + 2].x, v2.x, a2);
            a2 = fmaf(w[k + 2].y, v2.y, a2);
            a2 = fmaf(w[k + 2].z, v2.z, a2);
            a2 = fmaf(w[k + 2].w, v2.w, a2);
            a3 = fmaf(w[k + 3].x, v3.x, a3);
            a3 = fmaf(w[k + 3].y, v3.y, a3);
            a3 = fmaf(w[k + 3].z, v3.z, a3);
            a3 = fmaf(w[k + 3].w, v3.w, a3);
        }
        float acc = fmaf(x_lds[step], wih, bias) + ((a0 + a1) + (a2 + a3));
        float act = is_g ? fast_tanh(acc) : fast_sigmoid(acc);
        g_lds[t] = act;
        __syncthreads();  // g_lds ready; all h_lds reads of this step done

        // ================= phase B: wave 0 only =====================
        if (t < 64) {
            float i0 = g_lds[t];
            float i1 = g_lds[t + 64];
            float f0 = g_lds[128 + t];
            float f1 = g_lds[192 + t];
            float g0 = g_lds[256 + t];
            float g1 = g_lds[320 + t];
            float o0 = g_lds[384 + t];
            float o1 = g_lds[448 + t];
            c0 = fmaf(f0, c0, i0 * g0);
            c1 = fmaf(f1, c1, i1 * g1);
            float h0 = o0 * fast_tanh(c0);
            float h1 = o1 * fast_tanh(c1);
            h_lds[t]      = h0;
            h_lds[t + 64] = h1;
            // fused fc: out[b,step] = tanh(dot(h, fc_w) + fc_b)
            float p = fmaf(h0, fcw0, h1 * fcw1);
#pragma unroll
            for (int m = 32; m >= 1; m >>= 1) p += __shfl_xor(p, m, 64);
            if (t == 0) outp[step] = fast_tanh(p + fcb);
        }
        __syncthreads();  // h_lds ready for next step
    }

    // ---- final hT, cT (PyTorch layout: [1, B, H] each) ----
    if (t < 64) {
        float* hT = out + (size_t)NB * NT;
        float* cT = hT + (size_t)NB * NH;
        hT[b * NH + t]      = h_lds[t];
        hT[b * NH + t + 64] = h_lds[t + 64];
        cT[b * NH + t]      = c0;
        cT[b * NH + t + 64] = c1;
    }
}

extern "C" void kernel_launch(void* const* d_in, const int* in_sizes, int n_in,
                              void* d_out, int out_size, void* d_ws, size_t ws_size,
                              hipStream_t stream) {
    const float* x    = (const float*)d_in[0];
    const float* W_ih = (const float*)d_in[1];
    const float* W_hh = (const float*)d_in[2];
    const float* b_ih = (const float*)d_in[3];
    const float* b_hh = (const float*)d_in[4];
    const float* fc_w = (const float*)d_in[5];
    const float* fc_b = (const float*)d_in[6];
    float* out = (float*)d_out;

    lstm_fused_kernel<<<dim3(NB), dim3(512), 0, stream>>>(
        x, W_ih, W_hh, b_ih, b_hh, fc_w, fc_b, out);
}

// Round 2
// 1851.674 us; speedup vs baseline: 1.2433x; 1.2433x over previous
//
#include <hip/hip_runtime.h>

// LSTM: B=256, T=2048, H=128, gates 4H=512. One batch row per WG (256 WGs),
// 512 threads: thread t owns gate row t of W_hh as 64 packed half2 in VGPRs
// (asm-pinned so the compiler cannot sink the loads into the step loop —
// round-1 failure mode: VGPR=84 proved weights were re-loaded every step).
// Dot product via v_dot2_f32_f16: fp16 multiply, fp32 accumulate.
// Per step: phase A (512 threads: dot from h_lds fp16 + activation -> g_lds),
// barrier, phase B (wave 0: c/h update, fused fc + wave reduce), barrier.

typedef _Float16 half2v __attribute__((ext_vector_type(2)));

constexpr int NB = 256;   // batch
constexpr int NT = 2048;  // time steps
constexpr int NH = 128;   // hidden
constexpr int NG = 512;   // 4*NH gate rows

__device__ __forceinline__ float fast_sigmoid(float x) {
    x = fminf(fmaxf(x, -30.f), 30.f);
    return 1.f / (1.f + __expf(-x));
}

__device__ __forceinline__ float fast_tanh(float x) {
    x = fminf(fmaxf(x, -15.f), 15.f);
    float e = __expf(-2.f * x);
    return (1.f - e) / (1.f + e);
}

__device__ __forceinline__ float dot2(unsigned int w, unsigned int h, float acc) {
    half2v a = __builtin_bit_cast(half2v, w);
    half2v b = __builtin_bit_cast(half2v, h);
#if __has_builtin(__builtin_amdgcn_fdot2)
    return __builtin_amdgcn_fdot2(a, b, acc, false);
#else
    float r;
    asm("v_dot2_f32_f16 %0, %1, %2, %3" : "=v"(r) : "v"(a), "v"(b), "v"(acc));
    return r;
#endif
}

__global__ __launch_bounds__(512, 2) void lstm_fdot2_kernel(
    const float* __restrict__ x, const float* __restrict__ W_ih,
    const float* __restrict__ W_hh, const float* __restrict__ b_ih,
    const float* __restrict__ b_hh, const float* __restrict__ fc_w,
    const float* __restrict__ fc_b, float* __restrict__ out) {
    __shared__ __align__(16) float    x_lds[NT];   // this batch's input row (fp32)
    __shared__ __align__(16) _Float16 h_lds[NH];   // hidden state (fp16)
    __shared__ __align__(16) float    g_lds[NG];   // activated gates (fp32)

    const int b = blockIdx.x;
    const int t = threadIdx.x;  // 0..511 = gate row index

    // ---- preload x row (coalesced float4) ----
    {
        const float4* xs = (const float4*)(x + (size_t)b * NT);
        ((float4*)x_lds)[t] = xs[t];
    }
    if (t < NH) h_lds[t] = (_Float16)0.f;

    // ---- per-thread weights: row t of W_hh, fp32 -> packed fp16 (64 VGPRs) ----
    unsigned int wq[64];
    {
        const float2* wr = (const float2*)(W_hh + (size_t)t * NH);
#pragma unroll
        for (int k = 0; k < 64; ++k) {
            float2 f = wr[k];
            half2v p;
            p.x = (_Float16)f.x;
            p.y = (_Float16)f.y;
            wq[k] = __builtin_bit_cast(unsigned int, p);
        }
    }
    // Pin: asm "modifies" each value so loads can't be rematerialized in-loop.
#pragma unroll
    for (int k = 0; k < 64; ++k) asm volatile("" : "+v"(wq[k]));

    const float wih  = W_ih[t];
    const float bias = b_ih[t] + b_hh[t];
    const bool  is_g = ((t >> 7) == 2);  // rows 256..383 use tanh

    // ---- phase-B state (wave 0 only; lane l owns hidden units l and l+64) ----
    float c0 = 0.f, c1 = 0.f;
    float fcw0 = 0.f, fcw1 = 0.f, fcb = 0.f;
    if (t < 64) {
        fcw0 = fc_w[t];
        fcw1 = fc_w[t + 64];
        fcb  = fc_b[0];
    }

    float* outp = out + (size_t)b * NT;

    __syncthreads();

    for (int step = 0; step < NT; ++step) {
        // ============ phase A: all 512 threads: gate pre-act + activation ============
        float a0 = 0.f, a1 = 0.f, a2 = 0.f, a3 = 0.f;
        const uint4* h4 = (const uint4*)h_lds;  // 16B = 8 halves per read (broadcast)
#pragma unroll
        for (int j = 0; j < 16; ++j) {
            uint4 hv = h4[j];
            a0 = dot2(wq[4 * j + 0], hv.x, a0);
            a1 = dot2(wq[4 * j + 1], hv.y, a1);
            a2 = dot2(wq[4 * j + 2], hv.z, a2);
            a3 = dot2(wq[4 * j + 3], hv.w, a3);
        }
        float acc = fmaf(x_lds[step], wih, bias) + ((a0 + a1) + (a2 + a3));
        float act = is_g ? fast_tanh(acc) : fast_sigmoid(acc);
        g_lds[t] = act;
        __syncthreads();  // g_lds ready; all h_lds reads of this step done

        // ============ phase B: wave 0 only: cell update + fused fc ============
        if (t < 64) {
            float i0 = g_lds[t];
            float i1 = g_lds[t + 64];
            float f0 = g_lds[128 + t];
            float f1 = g_lds[192 + t];
            float g0 = g_lds[256 + t];
            float g1 = g_lds[320 + t];
            float o0 = g_lds[384 + t];
            float o1 = g_lds[448 + t];
            c0 = fmaf(f0, c0, i0 * g0);
            c1 = fmaf(f1, c1, i1 * g1);
            float h0 = o0 * fast_tanh(c0);
            float h1 = o1 * fast_tanh(c1);
            h_lds[t]      = (_Float16)h0;
            h_lds[t + 64] = (_Float16)h1;
            // fused fc: out[b,step] = tanh(dot(h, fc_w) + fc_b)  (fp32 h here)
            float p = fmaf(h0, fcw0, h1 * fcw1);
#pragma unroll
            for (int m = 32; m >= 1; m >>= 1) p += __shfl_xor(p, m, 64);
            if (t == 0) outp[step] = fast_tanh(p + fcb);
        }
        __syncthreads();  // h_lds ready for next step
    }

    // ---- final hT, cT ([1,B,H] each, concatenated after out) ----
    if (t < 64) {
        float* hT = out + (size_t)NB * NT;
        float* cT = hT + (size_t)NB * NH;
        float h0 = (float)h_lds[t];
        float h1 = (float)h_lds[t + 64];
        hT[b * NH + t]      = h0;
        hT[b * NH + t + 64] = h1;
        cT[b * NH + t]      = c0;
        cT[b * NH + t + 64] = c1;
    }
}

extern "C" void kernel_launch(void* const* d_in, const int* in_sizes, int n_in,
                              void* d_out, int out_size, void* d_ws, size_t ws_size,
                              hipStream_t stream) {
    const float* x    = (const float*)d_in[0];
    const float* W_ih = (const float*)d_in[1];
    const float* W_hh = (const float*)d_in[2];
    const float* b_ih = (const float*)d_in[3];
    const float* b_hh = (const float*)d_in[4];
    const float* fc_w = (const float*)d_in[5];
    const float* fc_b = (const float*)d_in[6];
    float* out = (float*)d_out;

    lstm_fdot2_kernel<<<dim3(NB), dim3(512), 0, stream>>>(
        x, W_ih, W_hh, b_ih, b_hh, fc_w, fc_b, out);
}

// Round 3
// 1220.251 us; speedup vs baseline: 1.8867x; 1.5175x over previous
//
#include <hip/hip_runtime.h>

// LSTM B=256, T=2048, H=128, gates 4H=512, fused fc output.
// Kernel 1: one batch row per WG (256 WGs), 1024 threads.
//   Thread t -> gate g = t&511, K-half = t>>9. Each thread holds HALF a W_hh
//   row as 32 packed half2 (~60 VGPR total demand -> stays in arch VGPRs;
//   round-2 failure: 64 half2 forced AGPR parking, +1 accvgpr_read per use).
//   Phase A: partial dot (v_dot2_f32_f16) -> ga/gb. Barrier.
//   Phase B: t<128: combine halves, activate (exp2/rcp), cell update,
//   h -> LDS (fp16) + fire-and-forget global store to d_ws. Raw barrier
//   (no vmcnt drain). fc projection runs as a separate memory-bound kernel.

typedef _Float16 half2v __attribute__((ext_vector_type(2)));

constexpr int NB = 256;
constexpr int NT = 2048;
constexpr int NH = 128;
constexpr int NG = 512;

__device__ __forceinline__ float fexp2(float x) {
    float r;
    asm("v_exp_f32 %0, %1" : "=v"(r) : "v"(x));
    return r;
}
__device__ __forceinline__ float frcp(float x) {
    float r;
    asm("v_rcp_f32 %0, %1" : "=v"(r) : "v"(x));
    return r;
}
// sigmoid(x) = 1/(1+2^(-x*log2e));  x->-inf: rcp(inf)=0; x->+inf: rcp(1)=1
__device__ __forceinline__ float fsig(float x) {
    return frcp(1.f + fexp2(x * -1.44269504f));
}
// tanh(x) = 2/(1+2^(-2x*log2e)) - 1; saturates correctly at +-1, no NaN
__device__ __forceinline__ float ftanh(float x) {
    return fmaf(2.f, frcp(1.f + fexp2(x * -2.88539008f)), -1.f);
}

__device__ __forceinline__ float dot2(unsigned int w, unsigned int h, float acc) {
    half2v a = __builtin_bit_cast(half2v, w);
    half2v b = __builtin_bit_cast(half2v, h);
#if __has_builtin(__builtin_amdgcn_fdot2)
    return __builtin_amdgcn_fdot2(a, b, acc, false);
#else
    float r;
    asm("v_dot2_f32_f16 %0, %1, %2, %3" : "=v"(r) : "v"(a), "v"(b), "v"(acc));
    return r;
#endif
}

__device__ __forceinline__ unsigned packh2(float lo, float hi) {
    half2v p;
    p.x = (_Float16)lo;
    p.y = (_Float16)hi;
    return __builtin_bit_cast(unsigned, p);
}

// raw barrier: lgkmcnt(0) so LDS writes are visible, but NO vmcnt drain
// (keeps fire-and-forget global h stores off the critical path)
__device__ __forceinline__ void barrier_lds() {
    asm volatile("s_waitcnt lgkmcnt(0)" ::: "memory");
    __builtin_amdgcn_s_barrier();
    asm volatile("" ::: "memory");
}

template <bool DEFER_FC>
__global__ __launch_bounds__(1024, 4) void lstm_k1(
    const float* __restrict__ x, const float* __restrict__ W_ih,
    const float* __restrict__ W_hh, const float* __restrict__ b_ih,
    const float* __restrict__ b_hh, const float* __restrict__ fc_w,
    const float* __restrict__ fc_b, float* __restrict__ out,
    _Float16* __restrict__ hws) {
    __shared__ __align__(16) float    x_lds[NT];
    __shared__ __align__(16) _Float16 h_lds[NH];
    __shared__ __align__(16) float    ga[NG];   // K-half-0 partial pre-acts
    __shared__ __align__(16) float    gb[NG];   // K-half-1 partials

    const int b    = blockIdx.x;
    const int t    = threadIdx.x;   // 0..1023
    const int g    = t & (NG - 1);  // gate row 0..511
    const int khalf = t >> 9;       // 0 or 1

    // preload x row: 1024 threads x float2
    ((float2*)x_lds)[t] = ((const float2*)(x + (size_t)b * NT))[t];
    if (t < NH) h_lds[t] = (_Float16)0.f;

    // half row of W_hh as 32 packed half2 (fits arch VGPRs)
    unsigned wq[32];
    {
        const float2* wr = (const float2*)(W_hh + (size_t)g * NH + khalf * 64);
#pragma unroll
        for (int k = 0; k < 32; ++k) {
            float2 f = wr[k];
            wq[k] = packh2(f.x, f.y);
        }
    }
#pragma unroll
    for (int k = 0; k < 32; ++k) asm volatile("" : "+v"(wq[k]));

    const float wih  = (khalf == 0) ? W_ih[g] : 0.f;
    const float bias = (khalf == 0) ? (b_ih[g] + b_hh[g]) : 0.f;

    float c0 = 0.f, c1 = 0.f;  // DEFER: t<128 uses c0 only; else t<64 uses both
    float fcw0 = 0.f, fcw1 = 0.f, fcb = 0.f;
    if (!DEFER_FC && t < 64) {
        fcw0 = fc_w[t];
        fcw1 = fc_w[t + 64];
        fcb  = fc_b[0];
    }

    float*     outp = out + (size_t)b * NT;
    _Float16*  hrow = DEFER_FC ? (hws + (size_t)b * NT * NH) : (_Float16*)nullptr;
    float*     gout = khalf ? gb : ga;

    __syncthreads();

    for (int step = 0; step < NT; ++step) {
        // ---------- phase A: partial gate pre-activation ----------
        float a0 = 0.f, a1 = 0.f, a2 = 0.f, a3 = 0.f;
        const uint4* h4 = (const uint4*)h_lds;  // broadcast reads
#pragma unroll
        for (int j = 0; j < 8; ++j) {
            uint4 hv = h4[(khalf << 3) + j];
            a0 = dot2(wq[4 * j + 0], hv.x, a0);
            a1 = dot2(wq[4 * j + 1], hv.y, a1);
            a2 = dot2(wq[4 * j + 2], hv.z, a2);
            a3 = dot2(wq[4 * j + 3], hv.w, a3);
        }
        gout[g] = ((a0 + a1) + (a2 + a3)) + fmaf(x_lds[step], wih, bias);
        __syncthreads();  // partials visible (vmcnt drain here is ~1 step old)

        // ---------- phase B: combine + activate + cell update ----------
        if (DEFER_FC) {
            if (t < NH) {
                float gi = ga[t] + gb[t];
                float gf = ga[NH + t] + gb[NH + t];
                float gz = ga[2 * NH + t] + gb[2 * NH + t];
                float go = ga[3 * NH + t] + gb[3 * NH + t];
                float i = fsig(gi), f = fsig(gf), z = ftanh(gz), o = fsig(go);
                c0 = fmaf(f, c0, i * z);
                float h = o * ftanh(c0);
                h_lds[t] = (_Float16)h;
                hrow[(size_t)step * NH + t] = (_Float16)h;  // fire-and-forget
            }
        } else {
            if (t < 64) {
                float i0 = fsig(ga[t] + gb[t]);
                float i1 = fsig(ga[t + 64] + gb[t + 64]);
                float f0 = fsig(ga[128 + t] + gb[128 + t]);
                float f1 = fsig(ga[192 + t] + gb[192 + t]);
                float z0 = ftanh(ga[256 + t] + gb[256 + t]);
                float z1 = ftanh(ga[320 + t] + gb[320 + t]);
                float o0 = fsig(ga[384 + t] + gb[384 + t]);
                float o1 = fsig(ga[448 + t] + gb[448 + t]);
                c0 = fmaf(f0, c0, i0 * z0);
                c1 = fmaf(f1, c1, i1 * z1);
                float h0 = o0 * ftanh(c0);
                float h1 = o1 * ftanh(c1);
                h_lds[t]      = (_Float16)h0;
                h_lds[t + 64] = (_Float16)h1;
                float p = fmaf(h0, fcw0, h1 * fcw1);
#pragma unroll
                for (int m = 32; m >= 1; m >>= 1) p += __shfl_xor(p, m, 64);
                if (t == 0) outp[step] = ftanh(p + fcb);
            }
        }
        barrier_lds();  // h_lds visible; NO vmcnt drain
    }

    // ---------- final hT, cT ([1,B,H] each, after out) ----------
    float* hT = out + (size_t)NB * NT;
    float* cT = hT + (size_t)NB * NH;
    if (DEFER_FC) {
        if (t < NH) {
            hT[b * NH + t] = (float)h_lds[t];
            cT[b * NH + t] = c0;
        }
    } else {
        if (t < 64) {
            hT[b * NH + t]      = (float)h_lds[t];
            hT[b * NH + t + 64] = (float)h_lds[t + 64];
            cT[b * NH + t]      = c0;
            cT[b * NH + t + 64] = c1;
        }
    }
}

// Kernel 2: out[b,t] = tanh(dot(h[b,t,:], fc_w) + fc_b). Memory-bound.
__global__ __launch_bounds__(256) void fc_k2(const _Float16* __restrict__ hws,
                                             const float* __restrict__ fc_w,
                                             const float* __restrict__ fc_b,
                                             float* __restrict__ out) {
    __shared__ unsigned wlds[64];  // fc_w packed half2
    const int t = threadIdx.x;
    if (t < 64) {
        float2 f = ((const float2*)fc_w)[t];
        wlds[t] = packh2(f.x, f.y);
    }
    __syncthreads();

    const size_t idx = (size_t)blockIdx.x * 256 + t;  // (b,t) flat, < NB*NT
    const uint4* hp = (const uint4*)(hws + idx * NH);
    const uint4* wp = (const uint4*)wlds;
    float acc = 0.f;
#pragma unroll
    for (int j = 0; j < 16; ++j) {
        uint4 hv = hp[j];
        uint4 wv = wp[j];
        acc = dot2(hv.x, wv.x, acc);
        acc = dot2(hv.y, wv.y, acc);
        acc = dot2(hv.z, wv.z, acc);
        acc = dot2(hv.w, wv.w, acc);
    }
    out[idx] = ftanh(acc + fc_b[0]);
}

extern "C" void kernel_launch(void* const* d_in, const int* in_sizes, int n_in,
                              void* d_out, int out_size, void* d_ws, size_t ws_size,
                              hipStream_t stream) {
    const float* x    = (const float*)d_in[0];
    const float* W_ih = (const float*)d_in[1];
    const float* W_hh = (const float*)d_in[2];
    const float* b_ih = (const float*)d_in[3];
    const float* b_hh = (const float*)d_in[4];
    const float* fc_w = (const float*)d_in[5];
    const float* fc_b = (const float*)d_in[6];
    float* out = (float*)d_out;

    const size_t need = (size_t)NB * NT * NH * sizeof(_Float16);  // 128 MB
    if (ws_size >= need) {
        _Float16* hws = (_Float16*)d_ws;
        lstm_k1<true><<<dim3(NB), dim3(1024), 0, stream>>>(
            x, W_ih, W_hh, b_ih, b_hh, fc_w, fc_b, out, hws);
        fc_k2<<<dim3(NB * NT / 256), dim3(256), 0, stream>>>(hws, fc_w, fc_b, out);
    } else {
        lstm_k1<false><<<dim3(NB), dim3(1024), 0, stream>>>(
            x, W_ih, W_hh, b_ih, b_hh, fc_w, fc_b, out, nullptr);
    }
}